// Round 10
// baseline (256.432 us; speedup 1.0000x reference)
//
#include <hip/hip_runtime.h>
#include <hip/hip_bf16.h>

// SimpleTransformer fused implementation for MI355X (gfx950).
// B=8, L=1024, E=16, DK=64, set_dim=32, vdim=8, head=256.

#define LSEQ 1024
#define DK   64
#define EMB  16
#define VDIM 8
#define A2S  1032   // A2 row stride (floats): 16B-aligned rows, 8-bank skew/row

typedef __attribute__((ext_vector_type(8))) short bf16x8;
typedef __attribute__((ext_vector_type(4))) float f32x4;

__device__ __forceinline__ unsigned short f2bf(float f) {
  union { float f; unsigned u; } v; v.f = f;
  unsigned r = v.u + 0x7fffu + ((v.u >> 16) & 1u);  // round-to-nearest-even
  return (unsigned short)(r >> 16);
}

__device__ __forceinline__ f32x4 mfma16(bf16x8 a, bf16x8 b, f32x4 c) {
  return __builtin_amdgcn_mfma_f32_16x16x32_bf16(a, b, c, 0, 0, 0);
}

// ---------------------------------------------------------------------------
// prep: [0,512) q/k proj (16 rows/block, 8 outs/thread) | [512,1024) V-MLP
//       | [1024,1280) SetPhi | [1280,1288) zero summar.  Grid 1288.
// ---------------------------------------------------------------------------
__global__ __launch_bounds__(256) void prep_kernel(
    const float* __restrict__ x,  const float* __restrict__ WQ,  const float* __restrict__ WK,
    const float* __restrict__ VW1, const float* __restrict__ Vb1,
    const float* __restrict__ VW2, const float* __restrict__ Vb2,
    const float* __restrict__ VW3, const float* __restrict__ Vb3,
    const float* __restrict__ PW1, const float* __restrict__ Pb1,
    const float* __restrict__ PW2, const float* __restrict__ Pb2,
    const float* __restrict__ PW3, const float* __restrict__ Pb3,
    const float* __restrict__ PW4, const float* __restrict__ Pb4,
    unsigned short* __restrict__ qb, unsigned short* __restrict__ kb,
    unsigned short* __restrict__ phiT, float* __restrict__ vws,
    float* __restrict__ summar)
{
  __shared__ float s1[272];
  __shared__ float s2[272];
  int bid = blockIdx.x, tid = threadIdx.x;

  if (bid < 512) {
    // q/k projection: 16 rows/block; thread (r=tid>>4, cg=tid&15) does 8 cols.
    int row = bid * 16 + (tid >> 4);
    int c0 = (tid & 15) * 8;            // cols c0..c0+7 of the 128 (q|k) outputs
    const float* xr = x + row * EMB;
    f32x4 xv0 = *(const f32x4*)(xr);
    f32x4 xv1 = *(const f32x4*)(xr + 4);
    f32x4 xv2 = *(const f32x4*)(xr + 8);
    f32x4 xv3 = *(const f32x4*)(xr + 12);
    #pragma unroll
    for (int u = 0; u < 8; ++u) {
      int c = c0 + u;
      const float* wr = ((c < 64) ? WQ : WK) + (c & 63) * EMB;
      f32x4 wv0 = *(const f32x4*)(wr);
      f32x4 wv1 = *(const f32x4*)(wr + 4);
      f32x4 wv2 = *(const f32x4*)(wr + 8);
      f32x4 wv3 = *(const f32x4*)(wr + 12);
      float acc = xv0[0]*wv0[0]+xv0[1]*wv0[1]+xv0[2]*wv0[2]+xv0[3]*wv0[3]
                + xv1[0]*wv1[0]+xv1[1]*wv1[1]+xv1[2]*wv1[2]+xv1[3]*wv1[3]
                + xv2[0]*wv2[0]+xv2[1]*wv2[1]+xv2[2]*wv2[2]+xv2[3]*wv2[3]
                + xv3[0]*wv3[0]+xv3[1]*wv3[1]+xv3[2]*wv3[2]+xv3[3]*wv3[3];
      unsigned short* dst = (c < 64) ? qb : kb;
      dst[row * DK + (c & 63)] = f2bf(acc);
    }

  } else if (bid < 1024) {
    // V MLP: 16 rows/block, 16 threads/row
    int lb = bid - 512;
    int r = tid >> 4, cc = tid & 15;
    int row = lb * 16 + r;
    const float* xr = x + row * EMB;
    float acc = Vb1[cc];
    #pragma unroll
    for (int e4 = 0; e4 < 4; ++e4) {
      f32x4 wv = *(const f32x4*)(VW1 + cc * 16 + e4 * 4);
      acc += xr[e4*4+0]*wv[0] + xr[e4*4+1]*wv[1] + xr[e4*4+2]*wv[2] + xr[e4*4+3]*wv[3];
    }
    s1[r * 17 + cc] = fmaxf(acc, 0.f);
    __syncthreads();
    acc = Vb2[cc];
    #pragma unroll
    for (int e4 = 0; e4 < 4; ++e4) {
      f32x4 wv = *(const f32x4*)(VW2 + cc * 16 + e4 * 4);
      acc += s1[r*17+e4*4+0]*wv[0] + s1[r*17+e4*4+1]*wv[1] + s1[r*17+e4*4+2]*wv[2] + s1[r*17+e4*4+3]*wv[3];
    }
    s2[r * 17 + cc] = fmaxf(acc, 0.f);
    __syncthreads();
    if (cc < 8) {
      acc = Vb3[cc];
      #pragma unroll
      for (int e4 = 0; e4 < 4; ++e4) {
        f32x4 wv = *(const f32x4*)(VW3 + cc * 16 + e4 * 4);
        acc += s2[r*17+e4*4+0]*wv[0] + s2[r*17+e4*4+1]*wv[1] + s2[r*17+e4*4+2]*wv[2] + s2[r*17+e4*4+3]*wv[3];
      }
      vws[row * VDIM + cc] = 1.f / (1.f + __expf(-acc));
    }

  } else if (bid < 1280) {
    // SetPhi MLP over t=row/1023: 4 rows/block, 64 threads/row. bf16 out [32][1024].
    int lb = bid - 1024;
    int r = tid >> 6, cc = tid & 63;
    int row = lb * 4 + r;
    float t = (float)row * (1.0f / 1023.0f);
    s1[r * 65 + cc] = fmaxf(PW1[cc] * t + Pb1[cc], 0.f);
    __syncthreads();
    float acc = Pb2[cc];
    #pragma unroll
    for (int e4 = 0; e4 < 16; ++e4) {
      f32x4 wv = *(const f32x4*)(PW2 + cc * 64 + e4 * 4);
      acc += s1[r*65+e4*4+0]*wv[0] + s1[r*65+e4*4+1]*wv[1] + s1[r*65+e4*4+2]*wv[2] + s1[r*65+e4*4+3]*wv[3];
    }
    s2[r * 65 + cc] = fmaxf(acc, 0.f);
    __syncthreads();
    acc = Pb3[cc];
    #pragma unroll
    for (int e4 = 0; e4 < 16; ++e4) {
      f32x4 wv = *(const f32x4*)(PW3 + cc * 64 + e4 * 4);
      acc += s2[r*65+e4*4+0]*wv[0] + s2[r*65+e4*4+1]*wv[1] + s2[r*65+e4*4+2]*wv[2] + s2[r*65+e4*4+3]*wv[3];
    }
    s1[r * 65 + cc] = fmaxf(acc, 0.f);
    __syncthreads();
    if (cc < 32) {
      acc = Pb4[cc];
      #pragma unroll
      for (int e4 = 0; e4 < 16; ++e4) {
        f32x4 wv = *(const f32x4*)(PW4 + cc * 64 + e4 * 4);
        acc += s1[r*65+e4*4+0]*wv[0] + s1[r*65+e4*4+1]*wv[1] + s1[r*65+e4*4+2]*wv[2] + s1[r*65+e4*4+3]*wv[3];
      }
      phiT[cc * LSEQ + row] = f2bf(acc);  // phiT[c][d] = SetPhi[d][c]
    }

  } else {
    int idx = (bid - 1280) * 256 + tid;
    summar[idx] = 0.f;
  }
}

// ---------------------------------------------------------------------------
// attn: grid = 8 b * 64 i-tiles = 512 blocks, 512 threads (8 waves).
// All long-slack global loads (afr, pf) issued at kernel start, hidden under
// A2 zero-init. Wave w owns j-range [128w,128w+128). No sv_w: per-wave
// shuffle-reduce -> direct global atomics.
// ---------------------------------------------------------------------------
__global__ __launch_bounds__(512, 4) void attn_kernel(
    const unsigned short* __restrict__ qb, const unsigned short* __restrict__ kb,
    const unsigned short* __restrict__ phiT, const float* __restrict__ vws,
    const float* __restrict__ offs, float* __restrict__ summar)
{
  __shared__ float A2_s[16 * A2S];      // 66 KB folded-diagonal accumulator
  __shared__ float v_s[16][8];

  int bid = blockIdx.x;
  int b  = bid >> 6;
  int i0 = (bid & 63) << 4;
  int tid = threadIdx.x;
  int lane = tid & 63, w = tid >> 6;    // w in [0,8)
  int lr = lane & 15, lg = lane >> 4;

  // ---- issue ALL long-slack loads first (latency hides under init) ----
  const unsigned short* qrow = qb + (size_t)(b * LSEQ + i0 + lr) * DK + lg * 8;
  bf16x8 afr0 = *(const bf16x8*)qrow;
  bf16x8 afr1 = *(const bf16x8*)(qrow + 32);

  int ct = w & 1, kq = w >> 1;          // sv-GEMM role of this wave
  const unsigned short* ph = phiT + (ct * 16 + lr) * LSEQ + kq * 256 + lg * 8;
  bf16x8 pf[8];
  #pragma unroll
  for (int s = 0; s < 8; ++s) pf[s] = *(const bf16x8*)(ph + s * 32);

  const unsigned short* kbase = kb + (size_t)b * LSEQ * DK + (size_t)(w * 128 + lr) * DK + lg * 8;
  bf16x8 bk0[8];
  #pragma unroll
  for (int st = 0; st < 4; ++st) {
    bk0[2*st]   = *(const bf16x8*)(kbase + st * 16 * DK);
    bk0[2*st+1] = *(const bf16x8*)(kbase + st * 16 * DK + 32);
  }

  float off = offs[0];
  if (tid < 128) v_s[tid >> 3][tid & 7] = vws[(b * LSEQ + i0 + (tid >> 3)) * VDIM + (tid & 7)];

  for (int idx = tid; idx < 16 * A2S; idx += 512) A2_s[idx] = 0.f;
  __syncthreads();  // A2_s zero + v_s visible

  // group-1 K loads (hidden under group-0 compute)
  bf16x8 bk1[8];
  #pragma unroll
  for (int st = 0; st < 4; ++st) {
    bk1[2*st]   = *(const bf16x8*)(kbase + (st + 4) * 16 * DK);
    bk1[2*st+1] = *(const bf16x8*)(kbase + (st + 4) * 16 * DK + 32);
  }

  // ---- QK^T + sigmoid + diagonal-fold scatter ----
  #pragma unroll
  for (int st = 0; st < 4; ++st) {
    f32x4 acc = {0.f, 0.f, 0.f, 0.f};
    acc = mfma16(afr0, bk0[2*st], acc);
    acc = mfma16(afr1, bk0[2*st+1], acc);
    #pragma unroll
    for (int r2 = 0; r2 < 4; ++r2) {
      int row = 4 * lg + r2;
      int gi = i0 + row;
      int gj = w * 128 + st * 16 + lr;
      float s = (gi == gj) ? 0.f : 1.f / (1.f + __expf(-(acc[r2] * 0.125f + off)));
      int d = gi - gj; d = (d < 0) ? -d : d;
      unsafeAtomicAdd(&A2_s[row * A2S + d], s);   // ds_add_f32
    }
  }
  #pragma unroll
  for (int st = 0; st < 4; ++st) {
    f32x4 acc = {0.f, 0.f, 0.f, 0.f};
    acc = mfma16(afr0, bk1[2*st], acc);
    acc = mfma16(afr1, bk1[2*st+1], acc);
    #pragma unroll
    for (int r2 = 0; r2 < 4; ++r2) {
      int row = 4 * lg + r2;
      int gi = i0 + row;
      int gj = w * 128 + (st + 4) * 16 + lr;
      float s = (gi == gj) ? 0.f : 1.f / (1.f + __expf(-(acc[r2] * 0.125f + off)));
      int d = gi - gj; d = (d < 0) ? -d : d;
      unsafeAtomicAdd(&A2_s[row * A2S + d], s);
    }
  }
  __syncthreads();  // all scatters done

  // ---- sv partial = A2[.,kq*256..+256) @ SetPhi-chunk via MFMA (8 steps) ----
  f32x4 acc = {0.f, 0.f, 0.f, 0.f};
  {
    const float* arow = A2_s + lr * A2S + kq * 256 + lg * 8;   // 16B-aligned
    #pragma unroll
    for (int s = 0; s < 8; ++s) {
      bf16x8 af;
      const float* ap = arow + s * 32;
      #pragma unroll
      for (int e = 0; e < 8; ++e) af[e] = (short)f2bf(ap[e]);
      acc = mfma16(af, pf[s], acc);
    }
  }

  // ---- per-wave reduce over rows and direct global atomic ----
  // lane(lg,lr) holds sv_p[4lg+r2][lr]; want Sum_il sv_p[il][lr]*v[il][kk].
  {
    float p[8];
    #pragma unroll
    for (int kk = 0; kk < 8; ++kk) p[kk] = 0.f;
    #pragma unroll
    for (int r2 = 0; r2 < 4; ++r2) {
      int row = 4 * lg + r2;
      f32x4 va = *(const f32x4*)&v_s[row][0];
      f32x4 vb = *(const f32x4*)&v_s[row][4];
      p[0] += acc[r2] * va[0];  p[1] += acc[r2] * va[1];
      p[2] += acc[r2] * va[2];  p[3] += acc[r2] * va[3];
      p[4] += acc[r2] * vb[0];  p[5] += acc[r2] * vb[1];
      p[6] += acc[r2] * vb[2];  p[7] += acc[r2] * vb[3];
    }
    #pragma unroll
    for (int kk = 0; kk < 8; ++kk) {
      p[kk] += __shfl_xor(p[kk], 16);
      p[kk] += __shfl_xor(p[kk], 32);
    }
    if (lg == 0) {
      float* dst = summar + b * 256 + (ct * 16 + lr) * 8;
      #pragma unroll
      for (int kk = 0; kk < 8; ++kk)
        unsafeAtomicAdd(&dst[kk], p[kk]);
    }
  }
}

// ---------------------------------------------------------------------------
// head: 8 blocks (one per batch), 1024 threads
// ---------------------------------------------------------------------------
__global__ __launch_bounds__(1024) void head_kernel(
    const float* __restrict__ summar,
    const float* __restrict__ HW1, const float* __restrict__ Hb1,
    const float* __restrict__ HW2, const float* __restrict__ Hb2,
    const float* __restrict__ HW3, const float* __restrict__ Hb3,
    float* __restrict__ out)
{
  __shared__ float fb[256];
  __shared__ float part[4][260];
  __shared__ float lgt[4];
  int b = blockIdx.x, tid = threadIdx.x;
  int c = tid & 255, qt = tid >> 8;

  if (qt == 0) fb[c] = summar[b * 256 + c];
  __syncthreads();
  {
    const float* wr = HW1 + c * 256 + qt * 64;
    const float* xr = fb + qt * 64;
    float a = 0.f;
    #pragma unroll
    for (int e = 0; e < 16; ++e) {
      f32x4 wv = *(const f32x4*)(wr + e * 4);
      f32x4 xv = *(const f32x4*)(xr + e * 4);
      a += wv[0]*xv[0] + wv[1]*xv[1] + wv[2]*xv[2] + wv[3]*xv[3];
    }
    part[qt][c] = a;
  }
  __syncthreads();
  if (qt == 0)
    fb[c] = fmaxf(part[0][c] + part[1][c] + part[2][c] + part[3][c] + Hb1[c], 0.f);
  __syncthreads();
  {
    const float* wr = HW2 + c * 256 + qt * 64;
    const float* xr = fb + qt * 64;
    float a = 0.f;
    #pragma unroll
    for (int e = 0; e < 16; ++e) {
      f32x4 wv = *(const f32x4*)(wr + e * 4);
      f32x4 xv = *(const f32x4*)(xr + e * 4);
      a += wv[0]*xv[0] + wv[1]*xv[1] + wv[2]*xv[2] + wv[3]*xv[3];
    }
    part[qt][c] = a;
  }
  __syncthreads();
  if (qt == 0)
    fb[c] = fmaxf(part[0][c] + part[1][c] + part[2][c] + part[3][c] + Hb2[c], 0.f);
  __syncthreads();
  if (tid < 4) {
    float a = Hb3[tid];
    for (int e = 0; e < 256; ++e) a += fb[e] * HW3[tid * 256 + e];
    lgt[tid] = a;
  }
  __syncthreads();
  if (tid == 0) {
    float m = fmaxf(fmaxf(lgt[0], lgt[1]), fmaxf(lgt[2], lgt[3]));
    float e0 = __expf(lgt[0] - m), e1 = __expf(lgt[1] - m);
    float e2 = __expf(lgt[2] - m), e3 = __expf(lgt[3] - m);
    float s = e0 + e1 + e2 + e3;
    out[b * 4 + 0] = e0 / s;
    out[b * 4 + 1] = e1 / s;
    out[b * 4 + 2] = e2 / s;
    out[b * 4 + 3] = e3 / s;
  }
}

// ---------------------------------------------------------------------------
extern "C" void kernel_launch(void* const* d_in, const int* in_sizes, int n_in,
                              void* d_out, int out_size, void* d_ws, size_t ws_size,
                              hipStream_t stream)
{
  const float* x   = (const float*)d_in[0];
  const float* WQ  = (const float*)d_in[1];
  const float* WK  = (const float*)d_in[2];
  const float* VW1 = (const float*)d_in[3];
  const float* Vb1 = (const float*)d_in[4];
  const float* VW2 = (const float*)d_in[5];
  const float* Vb2 = (const float*)d_in[6];
  const float* VW3 = (const float*)d_in[7];
  const float* Vb3 = (const float*)d_in[8];
  const float* PW1 = (const float*)d_in[9];
  const float* Pb1 = (const float*)d_in[10];
  const float* PW2 = (const float*)d_in[11];
  const float* Pb2 = (const float*)d_in[12];
  const float* PW3 = (const float*)d_in[13];
  const float* Pb3 = (const float*)d_in[14];
  const float* PW4 = (const float*)d_in[15];
  const float* Pb4 = (const float*)d_in[16];
  const float* offs= (const float*)d_in[17];
  const float* HW1 = (const float*)d_in[18];
  const float* Hb1 = (const float*)d_in[19];
  const float* HW2 = (const float*)d_in[20];
  const float* Hb2 = (const float*)d_in[21];
  const float* HW3 = (const float*)d_in[22];
  const float* Hb3 = (const float*)d_in[23];

  // workspace carve (bytes): qb 1MB | kb 1MB | phiT 64KB | v 256KB | summar 8KB
  char* ws = (char*)d_ws;
  unsigned short* qb   = (unsigned short*)(ws);
  unsigned short* kb   = (unsigned short*)(ws + (1u << 20));
  unsigned short* phiT = (unsigned short*)(ws + (2u << 20));
  float* vws    = (float*)(ws + (2u << 20) + (1u << 16));
  float* summar = (float*)(ws + (2u << 20) + (1u << 16) + (1u << 18));

  prep_kernel<<<dim3(1288), dim3(256), 0, stream>>>(
      x, WQ, WK, VW1, Vb1, VW2, Vb2, VW3, Vb3,
      PW1, Pb1, PW2, Pb2, PW3, Pb3, PW4, Pb4,
      qb, kb, phiT, vws, summar);

  attn_kernel<<<dim3(512), dim3(512), 0, stream>>>(
      qb, kb, phiT, vws, offs, summar);

  head_kernel<<<dim3(8), dim3(1024), 0, stream>>>(
      summar, HW1, Hb1, HW2, Hb2, HW3, Hb3, (float*)d_out);
}

// Round 12
// 193.223 us; speedup vs baseline: 1.3271x; 1.3271x over previous
//
#include <hip/hip_runtime.h>
#include <hip/hip_bf16.h>

// SimpleTransformer fused implementation for MI355X (gfx950).
// B=8, L=1024, E=16, DK=64, set_dim=32, vdim=8, head=256.
// R10 lesson: device-scope atomics on a tiny contended buffer dominated attn.
// This revision has ZERO global atomics: blocks write private partials,
// head_kernel reduces them.

#define LSEQ 1024
#define DK   64
#define EMB  16
#define VDIM 8
#define A2S  1026   // A2 row stride (floats): 2-bank skew/row, conflict-free sv read
                    // (1032 regressed: 8-bank skew -> 4-row groups alias mod 32)

typedef __attribute__((ext_vector_type(8))) short bf16x8;
typedef __attribute__((ext_vector_type(4))) float f32x4;

__device__ __forceinline__ unsigned short f2bf(float f) {
  union { float f; unsigned u; } v; v.f = f;
  unsigned r = v.u + 0x7fffu + ((v.u >> 16) & 1u);  // round-to-nearest-even
  return (unsigned short)(r >> 16);
}

__device__ __forceinline__ f32x4 mfma16(bf16x8 a, bf16x8 b, f32x4 c) {
  return __builtin_amdgcn_mfma_f32_16x16x32_bf16(a, b, c, 0, 0, 0);
}

// ---------------------------------------------------------------------------
// prep: [0,512) q/k proj | [512,1024) V-MLP | [1024,1280) SetPhi.  Grid 1280.
// ---------------------------------------------------------------------------
__global__ __launch_bounds__(256) void prep_kernel(
    const float* __restrict__ x,  const float* __restrict__ WQ,  const float* __restrict__ WK,
    const float* __restrict__ VW1, const float* __restrict__ Vb1,
    const float* __restrict__ VW2, const float* __restrict__ Vb2,
    const float* __restrict__ VW3, const float* __restrict__ Vb3,
    const float* __restrict__ PW1, const float* __restrict__ Pb1,
    const float* __restrict__ PW2, const float* __restrict__ Pb2,
    const float* __restrict__ PW3, const float* __restrict__ Pb3,
    const float* __restrict__ PW4, const float* __restrict__ Pb4,
    unsigned short* __restrict__ qb, unsigned short* __restrict__ kb,
    unsigned short* __restrict__ phiT, float* __restrict__ vws)
{
  __shared__ float s1[272];
  __shared__ float s2[272];
  int bid = blockIdx.x, tid = threadIdx.x;

  if (bid < 512) {
    // q/k projection: 16 rows/block; thread (r=tid>>4, cg=tid&15) does 8 cols.
    int row = bid * 16 + (tid >> 4);
    int c0 = (tid & 15) * 8;
    const float* xr = x + row * EMB;
    f32x4 xv0 = *(const f32x4*)(xr);
    f32x4 xv1 = *(const f32x4*)(xr + 4);
    f32x4 xv2 = *(const f32x4*)(xr + 8);
    f32x4 xv3 = *(const f32x4*)(xr + 12);
    #pragma unroll
    for (int u = 0; u < 8; ++u) {
      int c = c0 + u;
      const float* wr = ((c < 64) ? WQ : WK) + (c & 63) * EMB;
      f32x4 wv0 = *(const f32x4*)(wr);
      f32x4 wv1 = *(const f32x4*)(wr + 4);
      f32x4 wv2 = *(const f32x4*)(wr + 8);
      f32x4 wv3 = *(const f32x4*)(wr + 12);
      float acc = xv0[0]*wv0[0]+xv0[1]*wv0[1]+xv0[2]*wv0[2]+xv0[3]*wv0[3]
                + xv1[0]*wv1[0]+xv1[1]*wv1[1]+xv1[2]*wv1[2]+xv1[3]*wv1[3]
                + xv2[0]*wv2[0]+xv2[1]*wv2[1]+xv2[2]*wv2[2]+xv2[3]*wv2[3]
                + xv3[0]*wv3[0]+xv3[1]*wv3[1]+xv3[2]*wv3[2]+xv3[3]*wv3[3];
      unsigned short* dst = (c < 64) ? qb : kb;
      dst[row * DK + (c & 63)] = f2bf(acc);
    }

  } else if (bid < 1024) {
    // V MLP: 16 rows/block, 16 threads/row
    int lb = bid - 512;
    int r = tid >> 4, cc = tid & 15;
    int row = lb * 16 + r;
    const float* xr = x + row * EMB;
    float acc = Vb1[cc];
    #pragma unroll
    for (int e4 = 0; e4 < 4; ++e4) {
      f32x4 wv = *(const f32x4*)(VW1 + cc * 16 + e4 * 4);
      acc += xr[e4*4+0]*wv[0] + xr[e4*4+1]*wv[1] + xr[e4*4+2]*wv[2] + xr[e4*4+3]*wv[3];
    }
    s1[r * 17 + cc] = fmaxf(acc, 0.f);
    __syncthreads();
    acc = Vb2[cc];
    #pragma unroll
    for (int e4 = 0; e4 < 4; ++e4) {
      f32x4 wv = *(const f32x4*)(VW2 + cc * 16 + e4 * 4);
      acc += s1[r*17+e4*4+0]*wv[0] + s1[r*17+e4*4+1]*wv[1] + s1[r*17+e4*4+2]*wv[2] + s1[r*17+e4*4+3]*wv[3];
    }
    s2[r * 17 + cc] = fmaxf(acc, 0.f);
    __syncthreads();
    if (cc < 8) {
      acc = Vb3[cc];
      #pragma unroll
      for (int e4 = 0; e4 < 4; ++e4) {
        f32x4 wv = *(const f32x4*)(VW3 + cc * 16 + e4 * 4);
        acc += s2[r*17+e4*4+0]*wv[0] + s2[r*17+e4*4+1]*wv[1] + s2[r*17+e4*4+2]*wv[2] + s2[r*17+e4*4+3]*wv[3];
      }
      vws[row * VDIM + cc] = 1.f / (1.f + __expf(-acc));
    }

  } else {
    // SetPhi MLP over t=row/1023: 4 rows/block, 64 threads/row. bf16 out [32][1024].
    int lb = bid - 1024;
    int r = tid >> 6, cc = tid & 63;
    int row = lb * 4 + r;
    float t = (float)row * (1.0f / 1023.0f);
    s1[r * 65 + cc] = fmaxf(PW1[cc] * t + Pb1[cc], 0.f);
    __syncthreads();
    float acc = Pb2[cc];
    #pragma unroll
    for (int e4 = 0; e4 < 16; ++e4) {
      f32x4 wv = *(const f32x4*)(PW2 + cc * 64 + e4 * 4);
      acc += s1[r*65+e4*4+0]*wv[0] + s1[r*65+e4*4+1]*wv[1] + s1[r*65+e4*4+2]*wv[2] + s1[r*65+e4*4+3]*wv[3];
    }
    s2[r * 65 + cc] = fmaxf(acc, 0.f);
    __syncthreads();
    acc = Pb3[cc];
    #pragma unroll
    for (int e4 = 0; e4 < 16; ++e4) {
      f32x4 wv = *(const f32x4*)(PW3 + cc * 64 + e4 * 4);
      acc += s2[r*65+e4*4+0]*wv[0] + s2[r*65+e4*4+1]*wv[1] + s2[r*65+e4*4+2]*wv[2] + s2[r*65+e4*4+3]*wv[3];
    }
    s1[r * 65 + cc] = fmaxf(acc, 0.f);
    __syncthreads();
    if (cc < 32) {
      acc = Pb4[cc];
      #pragma unroll
      for (int e4 = 0; e4 < 16; ++e4) {
        f32x4 wv = *(const f32x4*)(PW4 + cc * 64 + e4 * 4);
        acc += s1[r*65+e4*4+0]*wv[0] + s1[r*65+e4*4+1]*wv[1] + s1[r*65+e4*4+2]*wv[2] + s1[r*65+e4*4+3]*wv[3];
      }
      phiT[cc * LSEQ + row] = f2bf(acc);  // phiT[c][d] = SetPhi[d][c]
    }
  }
}

// ---------------------------------------------------------------------------
// attn: grid = 8 b * 64 i-tiles = 512 blocks, 512 threads (8 waves).
// Wave w owns j-range [128w,128w+128). Epilogue: shuffle reduce -> LDS
// combine -> PLAIN store to partials[bid][256]. No global atomics anywhere.
// ---------------------------------------------------------------------------
__global__ __launch_bounds__(512, 4) void attn_kernel(
    const unsigned short* __restrict__ qb, const unsigned short* __restrict__ kb,
    const unsigned short* __restrict__ phiT, const float* __restrict__ vws,
    const float* __restrict__ offs, float* __restrict__ partials)
{
  __shared__ float A2_s[16 * A2S];      // 65.7 KB folded-diagonal accumulator
  __shared__ float v_s[16][8];
  __shared__ float svp[8][16][8];       // per-wave epilogue partials

  int bid = blockIdx.x;
  int b  = bid >> 6;
  int i0 = (bid & 63) << 4;
  int tid = threadIdx.x;
  int lane = tid & 63, w = tid >> 6;    // w in [0,8)
  int lr = lane & 15, lg = lane >> 4;

  // ---- issue ALL long-slack loads first (latency hides under init) ----
  const unsigned short* qrow = qb + (size_t)(b * LSEQ + i0 + lr) * DK + lg * 8;
  bf16x8 afr0 = *(const bf16x8*)qrow;
  bf16x8 afr1 = *(const bf16x8*)(qrow + 32);

  int ct = w & 1, kq = w >> 1;          // sv-GEMM role of this wave
  const unsigned short* ph = phiT + (ct * 16 + lr) * LSEQ + kq * 256 + lg * 8;
  bf16x8 pf[8];
  #pragma unroll
  for (int s = 0; s < 8; ++s) pf[s] = *(const bf16x8*)(ph + s * 32);

  const unsigned short* kbase = kb + (size_t)b * LSEQ * DK + (size_t)(w * 128 + lr) * DK + lg * 8;
  bf16x8 bk0[8];
  #pragma unroll
  for (int st = 0; st < 4; ++st) {
    bk0[2*st]   = *(const bf16x8*)(kbase + st * 16 * DK);
    bk0[2*st+1] = *(const bf16x8*)(kbase + st * 16 * DK + 32);
  }

  float off = offs[0];
  if (tid < 128) v_s[tid >> 3][tid & 7] = vws[(b * LSEQ + i0 + (tid >> 3)) * VDIM + (tid & 7)];

  for (int idx = tid; idx < 16 * A2S; idx += 512) A2_s[idx] = 0.f;
  __syncthreads();  // A2_s zero + v_s visible

  // group-1 K loads (hidden under group-0 compute)
  bf16x8 bk1[8];
  #pragma unroll
  for (int st = 0; st < 4; ++st) {
    bk1[2*st]   = *(const bf16x8*)(kbase + (st + 4) * 16 * DK);
    bk1[2*st+1] = *(const bf16x8*)(kbase + (st + 4) * 16 * DK + 32);
  }

  // ---- QK^T + sigmoid + diagonal-fold scatter (LDS ds_add_f32) ----
  #pragma unroll
  for (int st = 0; st < 4; ++st) {
    f32x4 acc = {0.f, 0.f, 0.f, 0.f};
    acc = mfma16(afr0, bk0[2*st], acc);
    acc = mfma16(afr1, bk0[2*st+1], acc);
    #pragma unroll
    for (int r2 = 0; r2 < 4; ++r2) {
      int row = 4 * lg + r2;
      int gi = i0 + row;
      int gj = w * 128 + st * 16 + lr;
      float s = (gi == gj) ? 0.f : 1.f / (1.f + __expf(-(acc[r2] * 0.125f + off)));
      int d = gi - gj; d = (d < 0) ? -d : d;
      unsafeAtomicAdd(&A2_s[row * A2S + d], s);
    }
  }
  #pragma unroll
  for (int st = 0; st < 4; ++st) {
    f32x4 acc = {0.f, 0.f, 0.f, 0.f};
    acc = mfma16(afr0, bk1[2*st], acc);
    acc = mfma16(afr1, bk1[2*st+1], acc);
    #pragma unroll
    for (int r2 = 0; r2 < 4; ++r2) {
      int row = 4 * lg + r2;
      int gi = i0 + row;
      int gj = w * 128 + (st + 4) * 16 + lr;
      float s = (gi == gj) ? 0.f : 1.f / (1.f + __expf(-(acc[r2] * 0.125f + off)));
      int d = gi - gj; d = (d < 0) ? -d : d;
      unsafeAtomicAdd(&A2_s[row * A2S + d], s);
    }
  }
  __syncthreads();  // all scatters done

  // ---- sv partial = A2[.,kq*256..+256) @ SetPhi-chunk via MFMA (8 steps) ----
  f32x4 acc = {0.f, 0.f, 0.f, 0.f};
  {
    const float* arow = A2_s + lr * A2S + kq * 256 + lg * 8;
    #pragma unroll
    for (int s = 0; s < 8; ++s) {
      bf16x8 af;
      const float* ap = arow + s * 32;
      #pragma unroll
      for (int e = 0; e < 8; ++e) af[e] = (short)f2bf(ap[e]);
      acc = mfma16(af, pf[s], acc);
    }
  }

  // ---- per-wave reduce over rows; LDS combine; plain store ----
  {
    float p[8];
    #pragma unroll
    for (int kk = 0; kk < 8; ++kk) p[kk] = 0.f;
    #pragma unroll
    for (int r2 = 0; r2 < 4; ++r2) {
      int row = 4 * lg + r2;
      f32x4 va = *(const f32x4*)&v_s[row][0];
      f32x4 vb = *(const f32x4*)&v_s[row][4];
      p[0] += acc[r2] * va[0];  p[1] += acc[r2] * va[1];
      p[2] += acc[r2] * va[2];  p[3] += acc[r2] * va[3];
      p[4] += acc[r2] * vb[0];  p[5] += acc[r2] * vb[1];
      p[6] += acc[r2] * vb[2];  p[7] += acc[r2] * vb[3];
    }
    #pragma unroll
    for (int kk = 0; kk < 8; ++kk) {
      p[kk] += __shfl_xor(p[kk], 16);
      p[kk] += __shfl_xor(p[kk], 32);
    }
    if (lg == 0) {
      #pragma unroll
      for (int kk = 0; kk < 8; ++kk) svp[w][lr][kk] = p[kk];
    }
  }
  __syncthreads();

  if (tid < 256) {
    int sd = tid >> 3, kk = tid & 7;     // sd in [0,32), kk in [0,8)
    int c2 = sd >> 4, cl = sd & 15;      // c2 = ct of this output column
    float a = svp[c2][cl][kk] + svp[c2 + 2][cl][kk]
            + svp[c2 + 4][cl][kk] + svp[c2 + 6][cl][kk];
    partials[(size_t)bid * 256 + sd * 8 + kk] = a;   // plain store, no contention
  }
}

// ---------------------------------------------------------------------------
// head: 8 blocks (one per batch), 1024 threads.
// Phase 0: reduce partials[b*64..b*64+63][256] -> fb[256]. Then MLP + softmax.
// ---------------------------------------------------------------------------
__global__ __launch_bounds__(1024) void head_kernel(
    const float* __restrict__ partials,
    const float* __restrict__ HW1, const float* __restrict__ Hb1,
    const float* __restrict__ HW2, const float* __restrict__ Hb2,
    const float* __restrict__ HW3, const float* __restrict__ Hb3,
    float* __restrict__ out)
{
  __shared__ float fb[256];
  __shared__ float part[4][260];
  __shared__ float lgt[4];
  int b = blockIdx.x, tid = threadIdx.x;
  int c = tid & 255, qt = tid >> 8;

  // phase 0: summarized[b][c] = sum over 64 i-tile blocks
  {
    const float* pp = partials + ((size_t)b * 64 + qt * 16) * 256 + c;
    float a = 0.f;
    #pragma unroll
    for (int it = 0; it < 16; ++it) a += pp[it * 256];
    part[qt][c] = a;
  }
  __syncthreads();
  if (qt == 0) fb[c] = part[0][c] + part[1][c] + part[2][c] + part[3][c];
  __syncthreads();
  // layer 1
  {
    const float* wr = HW1 + c * 256 + qt * 64;
    const float* xr = fb + qt * 64;
    float a = 0.f;
    #pragma unroll
    for (int e = 0; e < 16; ++e) {
      f32x4 wv = *(const f32x4*)(wr + e * 4);
      f32x4 xv = *(const f32x4*)(xr + e * 4);
      a += wv[0]*xv[0] + wv[1]*xv[1] + wv[2]*xv[2] + wv[3]*xv[3];
    }
    part[qt][c] = a;
  }
  __syncthreads();
  if (qt == 0)
    fb[c] = fmaxf(part[0][c] + part[1][c] + part[2][c] + part[3][c] + Hb1[c], 0.f);
  __syncthreads();
  // layer 2
  {
    const float* wr = HW2 + c * 256 + qt * 64;
    const float* xr = fb + qt * 64;
    float a = 0.f;
    #pragma unroll
    for (int e = 0; e < 16; ++e) {
      f32x4 wv = *(const f32x4*)(wr + e * 4);
      f32x4 xv = *(const f32x4*)(xr + e * 4);
      a += wv[0]*xv[0] + wv[1]*xv[1] + wv[2]*xv[2] + wv[3]*xv[3];
    }
    part[qt][c] = a;
  }
  __syncthreads();
  if (qt == 0)
    fb[c] = fmaxf(part[0][c] + part[1][c] + part[2][c] + part[3][c] + Hb2[c], 0.f);
  __syncthreads();
  // layer 3 + softmax
  if (tid < 4) {
    float a = Hb3[tid];
    for (int e = 0; e < 256; ++e) a += fb[e] * HW3[tid * 256 + e];
    lgt[tid] = a;
  }
  __syncthreads();
  if (tid == 0) {
    float m = fmaxf(fmaxf(lgt[0], lgt[1]), fmaxf(lgt[2], lgt[3]));
    float e0 = __expf(lgt[0] - m), e1 = __expf(lgt[1] - m);
    float e2 = __expf(lgt[2] - m), e3 = __expf(lgt[3] - m);
    float s = e0 + e1 + e2 + e3;
    out[b * 4 + 0] = e0 / s;
    out[b * 4 + 1] = e1 / s;
    out[b * 4 + 2] = e2 / s;
    out[b * 4 + 3] = e3 / s;
  }
}

// ---------------------------------------------------------------------------
extern "C" void kernel_launch(void* const* d_in, const int* in_sizes, int n_in,
                              void* d_out, int out_size, void* d_ws, size_t ws_size,
                              hipStream_t stream)
{
  const float* x   = (const float*)d_in[0];
  const float* WQ  = (const float*)d_in[1];
  const float* WK  = (const float*)d_in[2];
  const float* VW1 = (const float*)d_in[3];
  const float* Vb1 = (const float*)d_in[4];
  const float* VW2 = (const float*)d_in[5];
  const float* Vb2 = (const float*)d_in[6];
  const float* VW3 = (const float*)d_in[7];
  const float* Vb3 = (const float*)d_in[8];
  const float* PW1 = (const float*)d_in[9];
  const float* Pb1 = (const float*)d_in[10];
  const float* PW2 = (const float*)d_in[11];
  const float* Pb2 = (const float*)d_in[12];
  const float* PW3 = (const float*)d_in[13];
  const float* Pb3 = (const float*)d_in[14];
  const float* PW4 = (const float*)d_in[15];
  const float* Pb4 = (const float*)d_in[16];
  const float* offs= (const float*)d_in[17];
  const float* HW1 = (const float*)d_in[18];
  const float* Hb1 = (const float*)d_in[19];
  const float* HW2 = (const float*)d_in[20];
  const float* Hb2 = (const float*)d_in[21];
  const float* HW3 = (const float*)d_in[22];
  const float* Hb3 = (const float*)d_in[23];

  // workspace carve (bytes): qb 1MB | kb 1MB | phiT 64KB | vws 256KB | partials 512KB
  char* ws = (char*)d_ws;
  unsigned short* qb   = (unsigned short*)(ws);
  unsigned short* kb   = (unsigned short*)(ws + (1u << 20));
  unsigned short* phiT = (unsigned short*)(ws + (2u << 20));
  float* vws      = (float*)(ws + (2u << 20) + (1u << 16));
  float* partials = (float*)(ws + (2u << 20) + (1u << 16) + (1u << 18));

  prep_kernel<<<dim3(1280), dim3(256), 0, stream>>>(
      x, WQ, WK, VW1, Vb1, VW2, Vb2, VW3, Vb3,
      PW1, Pb1, PW2, Pb2, PW3, Pb3, PW4, Pb4,
      qb, kb, phiT, vws);

  attn_kernel<<<dim3(512), dim3(512), 0, stream>>>(
      qb, kb, phiT, vws, offs, partials);

  head_kernel<<<dim3(8), dim3(1024), 0, stream>>>(
      partials, HW1, Hb1, HW2, Hb2, HW3, Hb3, (float*)d_out);
}